// Round 4
// baseline (1044.383 us; speedup 1.0000x reference)
//
#include <hip/hip_runtime.h>
#include <hip/hip_cooperative_groups.h>
#include <math.h>

namespace cg = cooperative_groups;

// Problem constants
#define BB   16
#define CIN  64
#define HH   256
#define WW   256

// d_ws layout (floats):
//   TW2 : [256 w][16 q][2]             = 8192 floats (32 KB)
//   Xg  : [16 b][512 mode][64 c][2]    = 1,048,576 floats (4 MB)
//   Yg  : [16 b][64 d][512 mode][2]    = 1,048,576 floats (4 MB)
//   Wt  : [512 mode][64 d][64 c][2]    = 4,194,304 floats (16 MB)

// LDS plan (per block): ldsf[9472] floats (37,888 B) + Ecs[256] float2 (2,048 B)
//   = 39,936 B  -> 4 blocks/CU (160 KB), 16 waves/CU.

// ================= phase 0: twiddles + weight transpose (2 tiles/block) ======
__device__ void dev_prep(int blk, int tid,
                         const float* __restrict__ w1, const float* __restrict__ w2,
                         float* __restrict__ Wt, float* __restrict__ TW2,
                         float* ldsf) {
    if (blk < 16) {   // twiddle table: 4096 entries
        int idx = blk * 256 + tid;
        int w = idx >> 4, q = idx & 15;
        int k = (q * w) & 255;
        float s, c;
        sincospif((float)k * (1.0f / 128.0f), &s, &c);
        TW2[2 * idx]     = c;
        TW2[2 * idx + 1] = s;
    }
    float2 (*tile)[33] = (float2(*)[33])ldsf;      // 32*33 complex = 8448 B
    for (int t2 = 0; t2 < 2; t2++) {
        int tileIdx = blk * 2 + t2;                // 2048 tiles total
        const int bt = tileIdx & 15, at = tileIdx >> 4;
        const int b0 = bt * 32, a0 = at * 32;      // b0: mode, a0: d*64+c
        const float2* __restrict__ src = (const float2*)((b0 < 256) ? w1 : w2);
        const int bbase = b0 & 255;
        __syncthreads();                            // LDS reuse across t2
#pragma unroll
        for (int k = 0; k < 4; k++) {
            int idx = k * 256 + tid;
            int r = idx >> 5, cl = idx & 31;       // r: A offset, cl: mode offset
            tile[r][cl] = src[(size_t)(a0 + r) * 256 + bbase + cl];
        }
        __syncthreads();
        float2* __restrict__ dst = (float2*)Wt;    // Wt[mode][d*64+c]
#pragma unroll
        for (int k = 0; k < 4; k++) {
            int idx = k * 256 + tid;
            int r = idx >> 5, cl = idx & 31;       // r: mode offset, cl: A offset
            dst[(size_t)(b0 + r) * 4096 + a0 + cl] = tile[cl][r];
        }
    }
}

// ================= phase 1: forward partial DFT, x -> Xg[b][mode][c] =========
__device__ void dev_fwd(int img, int tid,
                        const float* __restrict__ x, const float* __restrict__ TW2,
                        float* __restrict__ Xg, float* smem, const float2* Ecs) {
    const float* __restrict__ xi = x + (size_t)img * (HH * WW);

    float pr[16], pi[16];
#pragma unroll
    for (int q = 0; q < 16; q++) { pr[q] = 0.f; pi[q] = 0.f; }

    // staging geometry: thread loads float4 at (row j*32+hb, col 16s + colb)
    const int f4   = tid & 7;
    const int hb   = tid >> 3;                           // 0..31
    const int colb = ((f4 & 4) << 5) + (f4 & 3) * 4;     // 0..12 or 128..140

    float4 r[8];
#pragma unroll
    for (int j = 0; j < 8; j++)       // prefetch slab 0
        r[j] = *(const float4*)(xi + (size_t)(j * 32 + hb) * WW + colb);

    for (int s = 0; s < 8; s++) {
        asm volatile("s_waitcnt lgkmcnt(0)" ::: "memory");
        __builtin_amdgcn_s_barrier();
#pragma unroll
        for (int j = 0; j < 8; j++) {
            float* p = &smem[(j * 32 + hb) * 33 + f4 * 4];
            p[0] = r[j].x; p[1] = r[j].y; p[2] = r[j].z; p[3] = r[j].w;
        }
        if (s < 7) {
            const float* __restrict__ xs = xi + 16 * (s + 1) + colb;
#pragma unroll
            for (int j = 0; j < 8; j++)
                r[j] = *(const float4*)(xs + (size_t)(j * 32 + hb) * WW);
        }
        asm volatile("s_waitcnt lgkmcnt(0)" ::: "memory");
        __builtin_amdgcn_s_barrier();
        // Phase A (radix-2 over w): P[h,q] += tw(q,w)*(x[h,w] +/- x[h,w+128])
        const float* __restrict__ twp = TW2 + s * 512;   // uniform -> s_load
#pragma unroll 2
        for (int wl = 0; wl < 16; wl++) {
            float y0 = smem[tid * 33 + wl];
            float y1 = smem[tid * 33 + 16 + wl];
            float sp = y0 + y1, sm = y0 - y1;
#pragma unroll
            for (int q = 0; q < 16; q++) {
                float sel = (q & 1) ? sm : sp;
                float cc = twp[wl * 32 + 2 * q];
                float ss = twp[wl * 32 + 2 * q + 1];
                pr[q] = fmaf(sel,  cc, pr[q]);
                pi[q] = fmaf(sel, -ss, pi[q]);
            }
        }
    }

    // dump P to LDS (row stride 34 floats)
    asm volatile("s_waitcnt lgkmcnt(0)" ::: "memory");
    __builtin_amdgcn_s_barrier();
#pragma unroll
    for (int q = 0; q < 16; q++) {
        smem[tid * 34 + 2 * q]     = pr[q];
        smem[tid * 34 + 2 * q + 1] = pi[q];
    }
    asm volatile("s_waitcnt lgkmcnt(0)" ::: "memory");
    __builtin_amdgcn_s_barrier();

    // fold pass: row h := P[h]+P[h+128]; row h+128 := P[h]-P[h+128]
#pragma unroll
    for (int k = 0; k < 8; k++) {
        int idx = k * 256 + tid;
        int h = idx >> 4, q = idx & 15;
        float2 a  = *(const float2*)&smem[h * 34 + 2 * q];
        float2 bb = *(const float2*)&smem[(h + 128) * 34 + 2 * q];
        *(float2*)&smem[h * 34 + 2 * q]         = make_float2(a.x + bb.x, a.y + bb.y);
        *(float2*)&smem[(h + 128) * 34 + 2 * q] = make_float2(a.x - bb.x, a.y - bb.y);
    }
    asm volatile("s_waitcnt lgkmcnt(0)" ::: "memory");
    __builtin_amdgcn_s_barrier();

    // Phase B (radix-2 over h): thread parity picks U (even t) or V (odd t)
    {
        const int q  = tid & 15;
        const int tp = tid >> 4;
        const int t0 = tp;
        const int t1 = 240 + tp;
        const int rbase = (tp & 1) ? (128 * 34) : 0;
        float x0r = 0.f, x0i = 0.f, x1r = 0.f, x1i = 0.f;
        for (int h = 0; h < 128; h++) {
            float2 uv = *(const float2*)&smem[rbase + h * 34 + 2 * q];
            float2 e0 = Ecs[(t0 * h) & 255];
            float2 e1 = Ecs[(t1 * h) & 255];
            x0r = fmaf(uv.x, e0.x, fmaf(uv.y,  e0.y, x0r));
            x0i = fmaf(uv.y, e0.x, fmaf(uv.x, -e0.y, x0i));
            x1r = fmaf(uv.x, e1.x, fmaf(uv.y,  e1.y, x1r));
            x1i = fmaf(uv.y, e1.x, fmaf(uv.x, -e1.y, x1i));
        }
        const float sc = 1.0f / 256.0f;
        const int b = img >> 6, c = img & 63;
        size_t o0 = ((size_t)b * 512 + (tp * 16 + q)) * 64 + c;
        size_t o1 = ((size_t)b * 512 + ((16 + tp) * 16 + q)) * 64 + c;
        Xg[2 * o0]     = x0r * sc;
        Xg[2 * o0 + 1] = x0i * sc;
        Xg[2 * o1]     = x1r * sc;
        Xg[2 * o1 + 1] = x1i * sc;
    }
}

// ================= phase 2: channel mix, Xg -> Yg[b][d][mode] ================
// block = mode*2 + half; W[mode] staged once in LDS, broadcast across c-loop.
__device__ void dev_mix(int blk, int tid,
                        const float* __restrict__ Xg, const float* __restrict__ Wt,
                        float* __restrict__ Yg, float* ldsf) {
    const int mode = blk >> 1, hf = blk & 1;
    float2* Ws = (float2*)ldsf;               // [64][65] complex = 8320 floats
    float2* Xs = (float2*)(ldsf + 8320);      // [64 c][9 pad] complex = 1152 floats

    const float2* __restrict__ Wm = (const float2*)Wt + (size_t)mode * 4096;
#pragma unroll
    for (int j = 0; j < 16; j++) {            // 4096 complex contiguous
        int i = j * 256 + tid;                // d*64+c
        float2 v = Wm[i];
        Ws[(i >> 6) * 65 + (i & 63)] = v;
    }
    const float2* __restrict__ Xc = (const float2*)Xg;
#pragma unroll
    for (int j = 0; j < 2; j++) {             // 512 complex (8 b x 64 c)
        int i = j * 256 + tid;
        int bl = i >> 6, c = i & 63;
        float2 v = Xc[(((size_t)(hf * 8 + bl)) * 512 + mode) * 64 + c];
        Xs[c * 9 + bl] = v;
    }
    __syncthreads();

    const int bl = tid & 7, dg = tid >> 3;    // dg in [0,32)
    float y0r = 0.f, y0i = 0.f, y1r = 0.f, y1i = 0.f;
#pragma unroll 8
    for (int c = 0; c < 64; c++) {
        float2 xv = Xs[c * 9 + bl];
        float2 w0 = Ws[dg * 65 + c];
        float2 w1 = Ws[(dg + 32) * 65 + c];
        y0r = fmaf(xv.x, w0.x, fmaf(xv.y, -w0.y, y0r));
        y0i = fmaf(xv.x, w0.y, fmaf(xv.y,  w0.x, y0i));
        y1r = fmaf(xv.x, w1.x, fmaf(xv.y, -w1.y, y1r));
        y1i = fmaf(xv.x, w1.y, fmaf(xv.y,  w1.x, y1i));
    }
    const int bg = hf * 8 + bl;
    float2* __restrict__ Yw = (float2*)Yg;
    Yw[((size_t)(bg * 64 + dg))      * 512 + mode] = make_float2(y0r, y0i);
    Yw[((size_t)(bg * 64 + dg + 32)) * 512 + mode] = make_float2(y1r, y1i);
    __syncthreads();   // protect LDS before next phase reuses it
}

// ================= phase 3: inverse DFT, Yg -> out ===========================
__device__ void dev_inv(int img, int tid,
                        const float* __restrict__ Yg, const float* __restrict__ TW2,
                        float* __restrict__ out, float* stage, const float2* Ecs) {
    const float* __restrict__ Y = Yg + (size_t)img * 1024;  // 512 complex

    // Phase D: g[h,q] = sum_{t in S} Y[t,q] e^{+2pi i t h/256}, thread h=tid
    float gr[16], gi[16];
#pragma unroll
    for (int q = 0; q < 16; q++) { gr[q] = 0.f; gi[q] = 0.f; }
    const int h = tid;
    for (int j = 0; j < 32; j++) {
        int t = (j < 16) ? j : (224 + j);
        float2 e = Ecs[(t * h) & 255];
#pragma unroll
        for (int q = 0; q < 16; q++) {
            float yr = Y[j * 32 + 2 * q];      // uniform -> s_load
            float yv = Y[j * 32 + 2 * q + 1];
            gr[q] = fmaf(yr, e.x, fmaf(yv, -e.y, gr[q]));
            gi[q] = fmaf(yv, e.x, fmaf(yr,  e.y, gi[q]));
        }
    }

    // Phase E (radix-2 over w): out[w]=ae+ao, out[w+128]=ae-ao
    const size_t obase = (size_t)img * (HH * WW);
    const float k2 = 2.0f / 256.0f;
    const int f4   = tid & 7;
    const int hb   = tid >> 3;
    const int colb = ((f4 & 4) << 5) + (f4 & 3) * 4;
    for (int s = 0; s < 8; s++) {
        const float* __restrict__ twp = TW2 + s * 512;
        float v0[16], v1[16];
#pragma unroll 2
        for (int wl = 0; wl < 16; wl++) {
            float ae = 0.5f * gr[0];
            float ao = 0.f;
#pragma unroll
            for (int q = 1; q < 16; q++) {
                float cc = twp[wl * 32 + 2 * q];
                float ss = twp[wl * 32 + 2 * q + 1];
                if (q & 1) ao = fmaf(gr[q], cc, fmaf(gi[q], -ss, ao));
                else       ae = fmaf(gr[q], cc, fmaf(gi[q], -ss, ae));
            }
            v0[wl] = (ae + ao) * k2;
            v1[wl] = (ae - ao) * k2;
        }
        asm volatile("s_waitcnt lgkmcnt(0)" ::: "memory");
        __builtin_amdgcn_s_barrier();
#pragma unroll
        for (int wl = 0; wl < 16; wl++) {
            stage[h * 33 + wl]      = v0[wl];
            stage[h * 33 + 16 + wl] = v1[wl];
        }
        asm volatile("s_waitcnt lgkmcnt(0)" ::: "memory");
        __builtin_amdgcn_s_barrier();
#pragma unroll
        for (int j = 0; j < 8; j++) {
            const float* p = &stage[(j * 32 + hb) * 33 + f4 * 4];
            float4 v; v.x = p[0]; v.y = p[1]; v.z = p[2]; v.w = p[3];
            *(float4*)(out + obase + (size_t)(j * 32 + hb) * WW + 16 * s + colb) = v;
        }
    }
}

// ================= cooperative mega-kernel ===================================
__global__ __launch_bounds__(256, 4) void k_all(const float* __restrict__ x,
                                                const float* __restrict__ w1,
                                                const float* __restrict__ w2,
                                                float* __restrict__ outp,
                                                float* __restrict__ TW2,
                                                float* __restrict__ Xg,
                                                float* __restrict__ Yg,
                                                float* __restrict__ Wt) {
    __shared__ float  ldsf[9472];
    __shared__ float2 Ecs[256];
    const int tid = threadIdx.x, blk = blockIdx.x;
    {
        float s, c;
        sincospif((float)tid * (1.0f / 128.0f), &s, &c);
        Ecs[tid] = make_float2(c, s);
    }
    dev_prep(blk, tid, w1, w2, Wt, TW2, ldsf);
    cg::this_grid().sync();
    dev_fwd(blk, tid, x, TW2, Xg, ldsf, Ecs);
    cg::this_grid().sync();
    dev_mix(blk, tid, Xg, Wt, Yg, ldsf);
    cg::this_grid().sync();
    dev_inv(blk, tid, Yg, TW2, outp, ldsf, Ecs);
}

// ================= fallback standalone kernels ===============================
__global__ __launch_bounds__(256, 4) void k_prep2(const float* __restrict__ w1,
                                                  const float* __restrict__ w2,
                                                  float* __restrict__ Wt,
                                                  float* __restrict__ TW2) {
    __shared__ float ldsf[9472];
    dev_prep(blockIdx.x, threadIdx.x, w1, w2, Wt, TW2, ldsf);
}
__global__ __launch_bounds__(256, 4) void k_fwd2(const float* __restrict__ x,
                                                 const float* __restrict__ TW2,
                                                 float* __restrict__ Xg) {
    __shared__ float  ldsf[9472];
    __shared__ float2 Ecs[256];
    const int tid = threadIdx.x;
    float s, c;
    sincospif((float)tid * (1.0f / 128.0f), &s, &c);
    Ecs[tid] = make_float2(c, s);
    dev_fwd(blockIdx.x, tid, x, TW2, Xg, ldsf, Ecs);
}
__global__ __launch_bounds__(256, 4) void k_mix2(const float* __restrict__ Xg,
                                                 const float* __restrict__ Wt,
                                                 float* __restrict__ Yg) {
    __shared__ float ldsf[9472];
    dev_mix(blockIdx.x, threadIdx.x, Xg, Wt, Yg, ldsf);
}
__global__ __launch_bounds__(256, 4) void k_inv2(const float* __restrict__ Yg,
                                                 const float* __restrict__ TW2,
                                                 float* __restrict__ outp) {
    __shared__ float  ldsf[9472];
    __shared__ float2 Ecs[256];
    const int tid = threadIdx.x;
    float s, c;
    sincospif((float)tid * (1.0f / 128.0f), &s, &c);
    Ecs[tid] = make_float2(c, s);
    __syncthreads();
    dev_inv(blockIdx.x, tid, Yg, TW2, outp, ldsf, Ecs);
}

extern "C" void kernel_launch(void* const* d_in, const int* in_sizes, int n_in,
                              void* d_out, int out_size, void* d_ws, size_t ws_size,
                              hipStream_t stream) {
    const float* x  = (const float*)d_in[0];
    const float* w1 = (const float*)d_in[1];
    const float* w2 = (const float*)d_in[2];
    float* outp = (float*)d_out;

    float* TW2 = (float*)d_ws;           // 8192 floats
    float* Xg  = TW2 + 8192;             // 1,048,576 floats
    float* Yg  = Xg + 1048576;           // 1,048,576 floats
    float* Wt  = Yg + 1048576;           // 4,194,304 floats

    void* args[8] = { (void*)&x, (void*)&w1, (void*)&w2, (void*)&outp,
                      (void*)&TW2, (void*)&Xg, (void*)&Yg, (void*)&Wt };
    hipError_t e = hipLaunchCooperativeKernel((const void*)k_all,
                                              dim3(1024), dim3(256),
                                              args, 0, stream);
    if (e != hipSuccess) {   // fallback: plain 4-dispatch pipeline
        k_prep2<<<1024, 256, 0, stream>>>(w1, w2, Wt, TW2);
        k_fwd2 <<<1024, 256, 0, stream>>>(x, TW2, Xg);
        k_mix2 <<<1024, 256, 0, stream>>>(Xg, Wt, Yg);
        k_inv2 <<<1024, 256, 0, stream>>>(Yg, TW2, outp);
    }
}